// Round 1
// baseline (92.559 us; speedup 1.0000x reference)
//
#include <hip/hip_runtime.h>
#include <hip/hip_bf16.h>

typedef unsigned int uint32;

#define NPT 128        // grid nodes per dim
#define RNK 16         // TT rank
#define MIDROW 264     // bf16 elems per LDS row for mid cores (256 + 8 pad) = 528 B
#define MIDROW_U32 132
#define EDGEROW 20     // fp32 elems per LDS row for edge cores (16 + 4 pad) = 80 B
#define SMEM_BYTES (2*NPT*MIDROW*2 + 2*NPT*EDGEROW*4)   // 135168 + 20480 = 155648 B

__device__ __forceinline__ float bl(uint32 u){ return __uint_as_float(u << 16); }
__device__ __forceinline__ float bh(uint32 u){ return __uint_as_float(u & 0xffff0000u); }

// dot of v[0..15] with 16 bf16 packed in two uint4 (elements i ascending, pairs per u32)
__device__ __forceinline__ float dot16(const float* v, uint4 U0, uint4 U1) {
  float s0 = fmaf(v[1],  bh(U0.x), v[0]*bl(U0.x));
  s0 = fmaf(v[2],  bl(U0.y), s0); s0 = fmaf(v[3],  bh(U0.y), s0);
  float s1 = fmaf(v[5],  bh(U0.z), v[4]*bl(U0.z));
  s1 = fmaf(v[6],  bl(U0.w), s1); s1 = fmaf(v[7],  bh(U0.w), s1);
  float s2 = fmaf(v[9],  bh(U1.x), v[8]*bl(U1.x));
  s2 = fmaf(v[10], bl(U1.y), s2); s2 = fmaf(v[11], bh(U1.y), s2);
  float s3 = fmaf(v[13], bh(U1.z), v[12]*bl(U1.z));
  s3 = fmaf(v[14], bl(U1.w), s3); s3 = fmaf(v[15], bh(U1.w), s3);
  return (s0 + s1) + (s2 + s3);
}

// one middle-dim contraction: v <- v @ ((1-w)*Lo + w*Hi), core rows in LDS as [n][j*16+i] bf16
__device__ __forceinline__ void tt_mid(const uint32* __restrict__ base, float xc, float v[16]) {
  int n0 = (int)xc;
  float w = xc - (float)n0;
  int n1 = min(n0 + 1, NPT - 1);
  const uint32* r0 = base + n0 * MIDROW_U32;
  const uint32* r1 = base + n1 * MIDROW_U32;
  float nv[16];
#pragma unroll
  for (int j = 0; j < 16; ++j) {
    const uint4* p0 = (const uint4*)(r0 + j * 8);
    const uint4* p1 = (const uint4*)(r1 + j * 8);
    uint4 A0 = p0[0], A1 = p0[1];
    uint4 B0 = p1[0], B1 = p1[1];
    float a = dot16(v, A0, A1);
    float b = dot16(v, B0, B1);
    nv[j] = fmaf(w, b - a, a);
  }
#pragma unroll
  for (int j = 0; j < 16; ++j) v[j] = nv[j];
}

__device__ __forceinline__ float remap_clamp(float x) {
  float xr = (x + 1.0f) * 0.5f * (float)(NPT - 1);
  return fminf(fmaxf(xr, 0.0f), (float)(NPT - 1));
}

__global__ __launch_bounds__(1024) void tt_kernel(
    const float* __restrict__ x,  const float* __restrict__ g0,
    const float* __restrict__ g1, const float* __restrict__ g2,
    const float* __restrict__ g3, float* __restrict__ out, int npts)
{
  extern __shared__ char smem[];
  unsigned short* c1 = (unsigned short*)smem;          // [128][264] bf16
  unsigned short* c2 = c1 + NPT * MIDROW;              // [128][264] bf16
  float* c0 = (float*)(c2 + NPT * MIDROW);             // [128][20] fp32
  float* c3 = c0 + NPT * EDGEROW;                      // [128][20] fp32

  // Stage mid cores: global [i][n][j] fp32 -> LDS [n][j*16+i] bf16 (RNE)
  for (int t = threadIdx.x; t < RNK * NPT * RNK; t += blockDim.x) {
    int i = t >> 11;
    int n = (t >> 4) & (NPT - 1);
    int j = t & (RNK - 1);
    __hip_bfloat16 h1 = __float2bfloat16(g1[t]);
    __hip_bfloat16 h2 = __float2bfloat16(g2[t]);
    c1[n * MIDROW + j * 16 + i] = *(unsigned short*)&h1;
    c2[n * MIDROW + j * 16 + i] = *(unsigned short*)&h2;
  }
  // Stage edge cores (fp32): core0 [1][n][j] -> [n][j]; core3 [i][n][1] -> [n][i]
  for (int t = threadIdx.x; t < NPT * RNK; t += blockDim.x) {
    int n = t >> 4;
    int i = t & (RNK - 1);
    c0[n * EDGEROW + i] = g0[t];               // flat n*16+j == t
    c3[n * EDGEROW + i] = g3[i * NPT + n];
  }
  __syncthreads();

  int p = blockIdx.x * blockDim.x + threadIdx.x;
  if (p >= npts) return;
  float4 xv = reinterpret_cast<const float4*>(x)[p];

  float v[16];
  // dim 0: v = lerp of core0 rows
  {
    float xc = remap_clamp(xv.x);
    int n0 = (int)xc; float w = xc - (float)n0; int n1 = min(n0 + 1, NPT - 1);
    const float4* L = (const float4*)(c0 + n0 * EDGEROW);
    const float4* H = (const float4*)(c0 + n1 * EDGEROW);
#pragma unroll
    for (int k = 0; k < 4; ++k) {
      float4 l = L[k], h = H[k];
      v[4*k+0] = fmaf(w, h.x - l.x, l.x);
      v[4*k+1] = fmaf(w, h.y - l.y, l.y);
      v[4*k+2] = fmaf(w, h.z - l.z, l.z);
      v[4*k+3] = fmaf(w, h.w - l.w, l.w);
    }
  }
  // dims 1, 2
  tt_mid((const uint32*)c1, remap_clamp(xv.y), v);
  tt_mid((const uint32*)c2, remap_clamp(xv.z), v);
  // dim 3: dot with lerped core3 column
  float acc;
  {
    float xc = remap_clamp(xv.w);
    int n0 = (int)xc; float w = xc - (float)n0; int n1 = min(n0 + 1, NPT - 1);
    const float4* L = (const float4*)(c3 + n0 * EDGEROW);
    const float4* H = (const float4*)(c3 + n1 * EDGEROW);
    float a0 = 0.f, a1 = 0.f, a2 = 0.f, a3 = 0.f;
#pragma unroll
    for (int k = 0; k < 4; ++k) {
      float4 l = L[k], h = H[k];
      a0 = fmaf(v[4*k+0], fmaf(w, h.x - l.x, l.x), a0);
      a1 = fmaf(v[4*k+1], fmaf(w, h.y - l.y, l.y), a1);
      a2 = fmaf(v[4*k+2], fmaf(w, h.z - l.z, l.z), a2);
      a3 = fmaf(v[4*k+3], fmaf(w, h.w - l.w, l.w), a3);
    }
    acc = (a0 + a1) + (a2 + a3);
  }
  out[p] = acc;
}

extern "C" void kernel_launch(void* const* d_in, const int* in_sizes, int n_in,
                              void* d_out, int out_size, void* d_ws, size_t ws_size,
                              hipStream_t stream) {
  const float* x  = (const float*)d_in[0];
  const float* g0 = (const float*)d_in[1];
  const float* g1 = (const float*)d_in[2];
  const float* g2 = (const float*)d_in[3];
  const float* g3 = (const float*)d_in[4];
  float* out = (float*)d_out;

  int B = in_sizes[0] / 4;
  // >64 KB dynamic LDS needs the opt-in attribute (host-side call, capture-safe)
  hipFuncSetAttribute(reinterpret_cast<const void*>(tt_kernel),
                      hipFuncAttributeMaxDynamicSharedMemorySize, SMEM_BYTES);
  int block = 1024;
  int grid = (B + block - 1) / block;   // 256 blocks -> 1 per CU
  tt_kernel<<<grid, block, SMEM_BYTES, stream>>>(x, g0, g1, g2, g3, out, B);
}

// Round 2
// 83.268 us; speedup vs baseline: 1.1116x; 1.1116x over previous
//
#include <hip/hip_runtime.h>
#include <hip/hip_bf16.h>

typedef unsigned int uint32;
typedef unsigned short u16;

#define NPT 128        // grid nodes per dim
#define RNK 16         // TT rank
#define MIDROW 264     // bf16 elems per LDS row for mid cores (256 + 8 pad) = 528 B
#define MIDROW_U32 132
#define EDGEROW 20     // fp32 elems per LDS row for edge cores (16 + 4 pad) = 80 B
#define SMEM_BYTES (2*NPT*MIDROW*2 + 2*NPT*EDGEROW*4)   // 135168 + 20480 = 155648 B

#if defined(__has_builtin)
#if __has_builtin(__builtin_amdgcn_fdot2_f32_bf16)
#define HAVE_BFDOT2 1
#endif
#endif

__device__ __forceinline__ float bl(uint32 u){ return __uint_as_float(u << 16); }
__device__ __forceinline__ float bh(uint32 u){ return __uint_as_float(u & 0xffff0000u); }

#ifdef HAVE_BFDOT2
typedef __bf16 v2bf __attribute__((ext_vector_type(2)));
__device__ __forceinline__ v2bf bc(uint32 u){ return __builtin_bit_cast(v2bf, u); }

// dot of packed-bf16 v (8 u32) with 16 bf16 core elems in two uint4
__device__ __forceinline__ float dot16b(const uint32* vp, uint4 U0, uint4 U1) {
  float s0 = 0.f, s1 = 0.f;
  s0 = __builtin_amdgcn_fdot2_f32_bf16(bc(vp[0]), bc(U0.x), s0, false);
  s0 = __builtin_amdgcn_fdot2_f32_bf16(bc(vp[1]), bc(U0.y), s0, false);
  s0 = __builtin_amdgcn_fdot2_f32_bf16(bc(vp[2]), bc(U0.z), s0, false);
  s0 = __builtin_amdgcn_fdot2_f32_bf16(bc(vp[3]), bc(U0.w), s0, false);
  s1 = __builtin_amdgcn_fdot2_f32_bf16(bc(vp[4]), bc(U1.x), s1, false);
  s1 = __builtin_amdgcn_fdot2_f32_bf16(bc(vp[5]), bc(U1.y), s1, false);
  s1 = __builtin_amdgcn_fdot2_f32_bf16(bc(vp[6]), bc(U1.z), s1, false);
  s1 = __builtin_amdgcn_fdot2_f32_bf16(bc(vp[7]), bc(U1.w), s1, false);
  return s0 + s1;
}
#else
// fallback: unpack + fmaf
__device__ __forceinline__ float dot16(const float* v, uint4 U0, uint4 U1) {
  float s0 = fmaf(v[1],  bh(U0.x), v[0]*bl(U0.x));
  s0 = fmaf(v[2],  bl(U0.y), s0); s0 = fmaf(v[3],  bh(U0.y), s0);
  float s1 = fmaf(v[5],  bh(U0.z), v[4]*bl(U0.z));
  s1 = fmaf(v[6],  bl(U0.w), s1); s1 = fmaf(v[7],  bh(U0.w), s1);
  float s2 = fmaf(v[9],  bh(U1.x), v[8]*bl(U1.x));
  s2 = fmaf(v[10], bl(U1.y), s2); s2 = fmaf(v[11], bh(U1.y), s2);
  float s3 = fmaf(v[13], bh(U1.z), v[12]*bl(U1.z));
  s3 = fmaf(v[14], bl(U1.w), s3); s3 = fmaf(v[15], bh(U1.w), s3);
  return (s0 + s1) + (s2 + s3);
}
#endif

// one middle-dim contraction: v <- v @ ((1-w)*Lo + w*Hi), core rows in LDS as [n][j*16+i] bf16
__device__ __forceinline__ void tt_mid(const uint32* __restrict__ base, float xc, float v[16]) {
  int n0 = (int)xc;
  float w = xc - (float)n0;
  int n1 = min(n0 + 1, NPT - 1);
  const uint32* r0 = base + n0 * MIDROW_U32;
  const uint32* r1 = base + n1 * MIDROW_U32;

#ifdef HAVE_BFDOT2
  // pack v into bf16 pairs once per dim (amortized over 16 j)
  uint32 vp[8];
#pragma unroll
  for (int k = 0; k < 8; ++k) {
    __hip_bfloat16 l = __float2bfloat16(v[2*k]);
    __hip_bfloat16 h = __float2bfloat16(v[2*k+1]);
    vp[k] = (uint32)(*(u16*)&l) | ((uint32)(*(u16*)&h) << 16);
  }
#endif

  float nv[16];
#pragma unroll
  for (int j = 0; j < 16; ++j) {
    const uint4* p0 = (const uint4*)(r0 + j * 8);
    const uint4* p1 = (const uint4*)(r1 + j * 8);
    uint4 A0 = p0[0], A1 = p0[1];
    uint4 B0 = p1[0], B1 = p1[1];
#ifdef HAVE_BFDOT2
    float a = dot16b(vp, A0, A1);
    float b = dot16b(vp, B0, B1);
#else
    float a = dot16(v, A0, A1);
    float b = dot16(v, B0, B1);
#endif
    nv[j] = fmaf(w, b - a, a);
  }
#pragma unroll
  for (int j = 0; j < 16; ++j) v[j] = nv[j];
}

__device__ __forceinline__ float remap_clamp(float x) {
  float xr = (x + 1.0f) * 0.5f * (float)(NPT - 1);
  return fminf(fmaxf(xr, 0.0f), (float)(NPT - 1));
}

// block=1024, min 4 waves/EU -> VGPR budget 128 (LDS already caps us at 1 block/CU)
__global__ __launch_bounds__(1024, 4) void tt_kernel(
    const float* __restrict__ x,  const float* __restrict__ g0,
    const float* __restrict__ g1, const float* __restrict__ g2,
    const float* __restrict__ g3, float* __restrict__ out, int npts)
{
  extern __shared__ char smem[];
  unsigned short* c1 = (unsigned short*)smem;          // [128][264] bf16
  unsigned short* c2 = c1 + NPT * MIDROW;              // [128][264] bf16
  float* c0 = (float*)(c2 + NPT * MIDROW);             // [128][20] fp32
  float* c3 = c0 + NPT * EDGEROW;                      // [128][20] fp32

  // Stage mid cores: global [i][n][j] fp32 -> LDS [n][j*16+i] bf16 (RNE)
  for (int t = threadIdx.x; t < RNK * NPT * RNK; t += blockDim.x) {
    int i = t >> 11;
    int n = (t >> 4) & (NPT - 1);
    int j = t & (RNK - 1);
    __hip_bfloat16 h1 = __float2bfloat16(g1[t]);
    __hip_bfloat16 h2 = __float2bfloat16(g2[t]);
    c1[n * MIDROW + j * 16 + i] = *(u16*)&h1;
    c2[n * MIDROW + j * 16 + i] = *(u16*)&h2;
  }
  // Stage edge cores (fp32): core0 [1][n][j] -> [n][j]; core3 [i][n][1] -> [n][i]
  for (int t = threadIdx.x; t < NPT * RNK; t += blockDim.x) {
    int n = t >> 4;
    int i = t & (RNK - 1);
    c0[n * EDGEROW + i] = g0[t];               // flat n*16+j == t
    c3[n * EDGEROW + i] = g3[i * NPT + n];
  }
  __syncthreads();

  int p = blockIdx.x * blockDim.x + threadIdx.x;
  if (p >= npts) return;
  float4 xv = reinterpret_cast<const float4*>(x)[p];

  float v[16];
  // dim 0: v = lerp of core0 rows
  {
    float xc = remap_clamp(xv.x);
    int n0 = (int)xc; float w = xc - (float)n0; int n1 = min(n0 + 1, NPT - 1);
    const float4* L = (const float4*)(c0 + n0 * EDGEROW);
    const float4* H = (const float4*)(c0 + n1 * EDGEROW);
#pragma unroll
    for (int k = 0; k < 4; ++k) {
      float4 l = L[k], h = H[k];
      v[4*k+0] = fmaf(w, h.x - l.x, l.x);
      v[4*k+1] = fmaf(w, h.y - l.y, l.y);
      v[4*k+2] = fmaf(w, h.z - l.z, l.z);
      v[4*k+3] = fmaf(w, h.w - l.w, l.w);
    }
  }
  // dims 1, 2
  tt_mid((const uint32*)c1, remap_clamp(xv.y), v);
  tt_mid((const uint32*)c2, remap_clamp(xv.z), v);
  // dim 3: dot with lerped core3 column
  float acc;
  {
    float xc = remap_clamp(xv.w);
    int n0 = (int)xc; float w = xc - (float)n0; int n1 = min(n0 + 1, NPT - 1);
    const float4* L = (const float4*)(c3 + n0 * EDGEROW);
    const float4* H = (const float4*)(c3 + n1 * EDGEROW);
    float a0 = 0.f, a1 = 0.f, a2 = 0.f, a3 = 0.f;
#pragma unroll
    for (int k = 0; k < 4; ++k) {
      float4 l = L[k], h = H[k];
      a0 = fmaf(v[4*k+0], fmaf(w, h.x - l.x, l.x), a0);
      a1 = fmaf(v[4*k+1], fmaf(w, h.y - l.y, l.y), a1);
      a2 = fmaf(v[4*k+2], fmaf(w, h.z - l.z, l.z), a2);
      a3 = fmaf(v[4*k+3], fmaf(w, h.w - l.w, l.w), a3);
    }
    acc = (a0 + a1) + (a2 + a3);
  }
  out[p] = acc;
}

extern "C" void kernel_launch(void* const* d_in, const int* in_sizes, int n_in,
                              void* d_out, int out_size, void* d_ws, size_t ws_size,
                              hipStream_t stream) {
  const float* x  = (const float*)d_in[0];
  const float* g0 = (const float*)d_in[1];
  const float* g1 = (const float*)d_in[2];
  const float* g2 = (const float*)d_in[3];
  const float* g3 = (const float*)d_in[4];
  float* out = (float*)d_out;

  int B = in_sizes[0] / 4;
  // >64 KB dynamic LDS needs the opt-in attribute (host-side call, capture-safe)
  hipFuncSetAttribute(reinterpret_cast<const void*>(tt_kernel),
                      hipFuncAttributeMaxDynamicSharedMemorySize, SMEM_BYTES);
  int block = 1024;
  int grid = (B + block - 1) / block;   // 256 blocks -> 1 per CU
  tt_kernel<<<grid, block, SMEM_BYTES, stream>>>(x, g0, g1, g2, g3, out, B);
}